// Round 1
// baseline (507.270 us; speedup 1.0000x reference)
//
#include <hip/hip_runtime.h>

#define NN 4096
#define DD 256
#define TEMP 0.07f
#define RPB 4
#define BLK 256

// ---------------- transpose F [N][D] -> FT [D][N] ----------------
__global__ __launch_bounds__(256) void transpose_k(const float* __restrict__ F,
                                                   float* __restrict__ FT) {
    __shared__ float tile[32][33];
    int bx = blockIdx.x;            // D/32 = 8
    int by = blockIdx.y;            // N/32 = 128
    int tx = threadIdx.x & 31;
    int ty = threadIdx.x >> 5;      // 0..7
#pragma unroll
    for (int k = 0; k < 4; k++) {
        int row = by * 32 + ty + k * 8;     // n
        int col = bx * 32 + tx;             // d
        tile[ty + k * 8][tx] = F[row * DD + col];
    }
    __syncthreads();
#pragma unroll
    for (int k = 0; k < 4; k++) {
        int d = bx * 32 + ty + k * 8;
        int n = by * 32 + tx;
        FT[d * NN + n] = tile[tx][ty + k * 8];
    }
}

// ---------------- reductions ----------------
__device__ __forceinline__ float wave_sum(float v) {
#pragma unroll
    for (int off = 32; off > 0; off >>= 1) v += __shfl_xor(v, off, 64);
    return v;
}
__device__ __forceinline__ float wave_max(float v) {
#pragma unroll
    for (int off = 32; off > 0; off >>= 1) v = fmaxf(v, __shfl_xor(v, off, 64));
    return v;
}
__device__ __forceinline__ float block_sum(float v, float* scratch) {
    int lane = threadIdx.x & 63, wid = threadIdx.x >> 6;
    v = wave_sum(v);
    if (lane == 0) scratch[wid] = v;
    __syncthreads();
    float r = scratch[0] + scratch[1] + scratch[2] + scratch[3];
    __syncthreads();
    return r;
}
__device__ __forceinline__ float block_max(float v, float* scratch) {
    int lane = threadIdx.x & 63, wid = threadIdx.x >> 6;
    v = wave_max(v);
    if (lane == 0) scratch[wid] = v;
    __syncthreads();
    float r = fmaxf(fmaxf(scratch[0], scratch[1]), fmaxf(scratch[2], scratch[3]));
    __syncthreads();
    return r;
}

// ---------------- main fused kernel: RPB rows per block ----------------
__global__ __launch_bounds__(BLK) void supcon_k(const float* __restrict__ F,
                                                const float* __restrict__ FT,
                                                const int* __restrict__ labels,
                                                float* __restrict__ out) {
    __shared__ float srow[RPB][NN];   // 64 KB similarity rows
    __shared__ float sFi[RPB][DD];    // 4 KB
    __shared__ float scratch[8];

    const int tid = threadIdx.x;
    const int i0 = blockIdx.x * RPB;

    for (int idx = tid; idx < RPB * DD; idx += BLK) {
        int r = idx >> 8, d = idx & 255;
        sFi[r][d] = F[(i0 + r) * DD + d];
    }
    __syncthreads();

    int labi[RPB];
#pragma unroll
    for (int r = 0; r < RPB; r++) labi[r] = labels[i0 + r];

    float pmax_all[RPB], pmax_same[RPB], pmax_diff[RPB], pcnt[RPB];
#pragma unroll
    for (int r = 0; r < RPB; r++) {
        pmax_all[r] = -3.4e38f; pmax_same[r] = -3.4e38f; pmax_diff[r] = -3.4e38f;
        pcnt[r] = 0.0f;
    }

    // ---- pass 1: similarities + maxima + counts ----
    for (int jt = 0; jt < NN; jt += BLK) {
        int j = jt + tid;
        float acc[RPB] = {0.f, 0.f, 0.f, 0.f};
#pragma unroll 8
        for (int d = 0; d < DD; d++) {
            float v = FT[d * NN + j];
#pragma unroll
            for (int r = 0; r < RPB; r++) acc[r] = fmaf(v, sFi[r][d], acc[r]);
        }
        int labj = labels[j];
#pragma unroll
        for (int r = 0; r < RPB; r++) {
            float s = acc[r];
            srow[r][j] = s;
            pmax_all[r] = fmaxf(pmax_all[r], s);
            bool same = (labj == labi[r]);
            bool self = (j == i0 + r);
            if (same && !self) { pmax_same[r] = fmaxf(pmax_same[r], s); pcnt[r] += 1.0f; }
            if (!same)         { pmax_diff[r] = fmaxf(pmax_diff[r], s); }
        }
    }
    __syncthreads();

    float m_all[RPB], m_same[RPB], m_diff[RPB], cnt[RPB];
#pragma unroll
    for (int r = 0; r < RPB; r++) {
        m_all[r]  = block_max(pmax_all[r],  scratch);
        m_same[r] = block_max(pmax_same[r], scratch);
        m_diff[r] = block_max(pmax_diff[r], scratch);
        cnt[r]    = block_sum(pcnt[r],      scratch);
    }

    // ---- pass 2: masked softmax denominators ----
    float pA_same[RPB] = {0.f, 0.f, 0.f, 0.f};
    float pA_diff[RPB] = {0.f, 0.f, 0.f, 0.f};
    for (int j = tid; j < NN; j += BLK) {
        int labj = labels[j];
#pragma unroll
        for (int r = 0; r < RPB; r++) {
            float s = srow[r][j];
            bool same = (labj == labi[r]);
            bool self = (j == i0 + r);
            if (same && !self)      pA_same[r] += expf(s - m_same[r]);
            else if (!same)         pA_diff[r] += expf(s - m_diff[r]);
        }
    }
    float A_same[RPB], A_diff[RPB];
#pragma unroll
    for (int r = 0; r < RPB; r++) {
        A_same[r] = block_sum(pA_same[r], scratch);
        A_diff[r] = block_sum(pA_diff[r], scratch);
    }

    // ---- pass 3: Z, sum(w_same), sum(w_same*logit) ----
    const float invT = 1.0f / TEMP;
    float pZ[RPB] = {0.f, 0.f, 0.f, 0.f};
    float pQ[RPB] = {0.f, 0.f, 0.f, 0.f};
    float pP[RPB] = {0.f, 0.f, 0.f, 0.f};
    for (int j = tid; j < NN; j += BLK) {
        int labj = labels[j];
#pragma unroll
        for (int r = 0; r < RPB; r++) {
            float s = srow[r][j];
            bool same = (labj == labi[r]);
            bool self = (j == i0 + r);
            float w = 0.0f, wsame = 0.0f;
            if (same && !self) {
                float sm = expf(s - m_same[r]) / A_same[r];
                sm = fminf(fmaxf(sm, 1e-8f), 1.0f - 1e-8f);
                wsame = 1.0f - sm;
                w = wsame;
            } else if (!same) {
                float sm = expf(s - m_diff[r]) / A_diff[r];
                sm = fminf(fmaxf(sm, 1e-8f), 1.0f - 1e-8f);
                w = 1.0f + sm;
            }
            float l = (s - m_all[r]) * invT;
            pZ[r] += __expf(l) * w;   // l in [-29,0]; fast exp fine
            pQ[r] += l * wsame;
            pP[r] += wsame;
        }
    }
    float total = 0.0f;
#pragma unroll
    for (int r = 0; r < RPB; r++) {
        float Z = block_sum(pZ[r], scratch);
        float Q = block_sum(pQ[r], scratch);
        float P = block_sum(pP[r], scratch);
        if (tid == 0) {
            float logZ = logf(Z + 1e-8f);
            float ms = (cnt[r] == 0.0f) ? 1.0f : cnt[r];
            total += -(Q - P * logZ) / ms;
        }
    }
    if (tid == 0) atomicAdd(out, total / (float)NN);
}

extern "C" void kernel_launch(void* const* d_in, const int* in_sizes, int n_in,
                              void* d_out, int out_size, void* d_ws, size_t ws_size,
                              hipStream_t stream) {
    const float* F = (const float*)d_in[0];
    const int* labels = (const int*)d_in[1];
    float* out = (float*)d_out;
    float* FT = (float*)d_ws;   // 256*4096*4 = 4 MB

    hipMemsetAsync(out, 0, sizeof(float), stream);
    transpose_k<<<dim3(8, 128), 256, 0, stream>>>(F, FT);
    supcon_k<<<NN / RPB, BLK, 0, stream>>>(F, FT, labels, out);
}

// Round 2
// 193.520 us; speedup vs baseline: 2.6213x; 2.6213x over previous
//
#include <hip/hip_runtime.h>

#define NN 4096
#define DD 256
#define TEMP 0.07f
#define BLK 512          // 8 waves
#define IB 16            // i-rows per block
#define NTILE (NN / 16)  // 256 j-tiles of 16

typedef __attribute__((ext_vector_type(8))) short short8;
typedef __attribute__((ext_vector_type(4))) float f32x4;

__device__ __forceinline__ unsigned short f2bf(float x) {
    unsigned int b = __float_as_uint(x);
    unsigned int r = (b + 0x7fffu + ((b >> 16) & 1u)) >> 16;
    return (unsigned short)r;
}

// ---------------- convert F f32 -> bf16 ----------------
__global__ __launch_bounds__(256) void cvt_k(const float* __restrict__ F,
                                             unsigned short* __restrict__ Fb) {
    int idx = blockIdx.x * 256 + threadIdx.x;       // 262144 threads, 4 elems each
    float4 v = ((const float4*)F)[idx];
    ushort4 o;
    o.x = f2bf(v.x); o.y = f2bf(v.y); o.z = f2bf(v.z); o.w = f2bf(v.w);
    ((ushort4*)Fb)[idx] = o;
}

// online-softmax merge: (m1,A1) <- merge((m1,A1),(m2,A2))
__device__ __forceinline__ void osm_merge(float& m1, float& A1, float m2, float A2) {
    float nm = fmaxf(m1, m2);
    A1 = A1 * __expf(m1 - nm) + A2 * __expf(m2 - nm);
    m1 = nm;
}

// ---------------- fused SupCon kernel ----------------
__global__ __launch_bounds__(BLK) void supcon_k(const unsigned short* __restrict__ Fb,
                                                const int* __restrict__ labels,
                                                float* __restrict__ out) {
    __shared__ int slab[NN];               // 16 KB
    __shared__ float sstat[8][IB][6];      // per-wave online stats
    __shared__ float sfin[IB][6];          // merged per-row stats
    __shared__ float sred[8][IB][3];       // pass-B partials

    const int tid  = threadIdx.x;
    const int lane = tid & 63;
    const int wid  = tid >> 6;             // 0..7
    const int il   = lane & 15;            // this thread's output row (i) slot
    const int kg   = lane >> 4;            // 0..3 k-group
    const int i0   = blockIdx.x * IB;
    const int iglob = i0 + il;

    for (int j = tid; j < NN; j += BLK) slab[j] = labels[j];

    // B-fragment preload: rows i0..i0+15, B[k][col]=F[i0+col][k]
    short8 bfrag[8];
    {
        const short8* p = (const short8*)(Fb + (size_t)iglob * DD + kg * 8);
#pragma unroll
        for (int k0 = 0; k0 < 8; k0++) bfrag[k0] = p[k0 * 4];   // +64B per K-step
    }
    __syncthreads();

    const int labi = slab[iglob];

    // ---------------- pass A: online stats ----------------
    float m_all = -3.4e38f, m_s = -3.4e38f, m_d = -3.4e38f;
    float A_s = 0.f, A_d = 0.f, cnt = 0.f;

    for (int t = wid; t < NTILE; t += 8) {
        const int jbase = t * 16;
        const short8* ap = (const short8*)(Fb + (size_t)(jbase + il) * DD + kg * 8);
        f32x4 acc = {0.f, 0.f, 0.f, 0.f};
#pragma unroll
        for (int k0 = 0; k0 < 8; k0++)
            acc = __builtin_amdgcn_mfma_f32_16x16x32_bf16(ap[k0 * 4], bfrag[k0], acc, 0, 0, 0);
#pragma unroll
        for (int r = 0; r < 4; r++) {
            float s = acc[r];
            int j = jbase + kg * 4 + r;    // C row = (lane>>4)*4 + reg = local j
            m_all = fmaxf(m_all, s);
            int labj = slab[j];
            if (j != iglob) {
                if (labj == labi) {
                    float nm = fmaxf(m_s, s);
                    A_s = A_s * __expf(m_s - nm) + __expf(s - nm);
                    m_s = nm; cnt += 1.f;
                } else {
                    float nm = fmaxf(m_d, s);
                    A_d = A_d * __expf(m_d - nm) + __expf(s - nm);
                    m_d = nm;
                }
            }
        }
    }

    // cross-lane merge (j-coverage is split over kg groups)
#pragma unroll
    for (int off = 16; off < 64; off <<= 1) {
        float om, oA;
        om = __shfl_xor(m_s, off, 64); oA = __shfl_xor(A_s, off, 64); osm_merge(m_s, A_s, om, oA);
        om = __shfl_xor(m_d, off, 64); oA = __shfl_xor(A_d, off, 64); osm_merge(m_d, A_d, om, oA);
        m_all = fmaxf(m_all, __shfl_xor(m_all, off, 64));
        cnt  += __shfl_xor(cnt, off, 64);
    }
    if (lane < 16) {
        sstat[wid][il][0] = m_all; sstat[wid][il][1] = m_s; sstat[wid][il][2] = A_s;
        sstat[wid][il][3] = m_d;   sstat[wid][il][4] = A_d; sstat[wid][il][5] = cnt;
    }
    __syncthreads();
    if (tid < IB) {
        float fm_all = sstat[0][tid][0], fm_s = sstat[0][tid][1], fA_s = sstat[0][tid][2];
        float fm_d = sstat[0][tid][3], fA_d = sstat[0][tid][4], fcnt = sstat[0][tid][5];
        for (int w = 1; w < 8; w++) {
            fm_all = fmaxf(fm_all, sstat[w][tid][0]);
            osm_merge(fm_s, fA_s, sstat[w][tid][1], sstat[w][tid][2]);
            osm_merge(fm_d, fA_d, sstat[w][tid][3], sstat[w][tid][4]);
            fcnt += sstat[w][tid][5];
        }
        sfin[tid][0] = fm_all; sfin[tid][1] = fm_s; sfin[tid][2] = fA_s;
        sfin[tid][3] = fm_d;   sfin[tid][4] = fA_d; sfin[tid][5] = fcnt;
    }
    __syncthreads();

    const float fm_all = sfin[il][0], fm_s = sfin[il][1], fA_s = sfin[il][2];
    const float fm_d = sfin[il][3], fA_d = sfin[il][4];

    // ---------------- pass B: Z, Q, P ----------------
    const float invT = 1.0f / TEMP;
    float Z = 0.f, Q = 0.f, P = 0.f;
    for (int t = wid; t < NTILE; t += 8) {
        const int jbase = t * 16;
        const short8* ap = (const short8*)(Fb + (size_t)(jbase + il) * DD + kg * 8);
        f32x4 acc = {0.f, 0.f, 0.f, 0.f};
#pragma unroll
        for (int k0 = 0; k0 < 8; k0++)
            acc = __builtin_amdgcn_mfma_f32_16x16x32_bf16(ap[k0 * 4], bfrag[k0], acc, 0, 0, 0);
#pragma unroll
        for (int r = 0; r < 4; r++) {
            float s = acc[r];
            int j = jbase + kg * 4 + r;
            int labj = slab[j];
            if (j != iglob) {
                float l = (s - fm_all) * invT;
                float el = __expf(l);
                if (labj == labi) {
                    float sm = __expf(s - fm_s) / fA_s;
                    sm = fminf(fmaxf(sm, 1e-8f), 1.0f - 1e-8f);
                    float ws = 1.0f - sm;
                    Z += el * ws; Q += l * ws; P += ws;
                } else {
                    float sm = __expf(s - fm_d) / fA_d;
                    sm = fminf(fmaxf(sm, 1e-8f), 1.0f - 1e-8f);
                    Z += el * (1.0f + sm);
                }
            }
        }
    }
#pragma unroll
    for (int off = 16; off < 64; off <<= 1) {
        Z += __shfl_xor(Z, off, 64);
        Q += __shfl_xor(Q, off, 64);
        P += __shfl_xor(P, off, 64);
    }
    if (lane < 16) { sred[wid][il][0] = Z; sred[wid][il][1] = Q; sred[wid][il][2] = P; }
    __syncthreads();
    if (tid < IB) {
        float fZ = 0.f, fQ = 0.f, fP = 0.f;
        for (int w = 0; w < 8; w++) {
            fZ += sred[w][tid][0]; fQ += sred[w][tid][1]; fP += sred[w][tid][2];
        }
        float fcnt = sfin[tid][5];
        float ms = (fcnt == 0.0f) ? 1.0f : fcnt;
        float logZ = logf(fZ + 1e-8f);
        float loss_i = -(fQ - fP * logZ) / ms;
        atomicAdd(out, loss_i * (1.0f / (float)NN));
    }
}

extern "C" void kernel_launch(void* const* d_in, const int* in_sizes, int n_in,
                              void* d_out, int out_size, void* d_ws, size_t ws_size,
                              hipStream_t stream) {
    const float* F = (const float*)d_in[0];
    const int* labels = (const int*)d_in[1];
    float* out = (float*)d_out;
    unsigned short* Fb = (unsigned short*)d_ws;   // 4096*256*2 = 2 MB

    hipMemsetAsync(out, 0, sizeof(float), stream);
    cvt_k<<<NN * DD / 4 / 256, 256, 0, stream>>>(F, Fb);
    supcon_k<<<NN / IB, BLK, 0, stream>>>(Fb, labels, out);
}

// Round 3
// 139.134 us; speedup vs baseline: 3.6459x; 1.3909x over previous
//
#include <hip/hip_runtime.h>

#define NN 4096
#define DD 256
#define TEMP 0.07f
#define INV_T (1.0f / TEMP)
#define BLK 512
#define IB 64            // i-rows per block
#define JC 8             // j-chunks
#define JPC (NN / JC)    // 512 j per chunk
#define JT (JPC / 16)    // 32 j-tiles per chunk

typedef __attribute__((ext_vector_type(8))) short short8;
typedef __attribute__((ext_vector_type(4))) float f32x4;

__device__ __forceinline__ unsigned short f2bf(float x) {
    unsigned int b = __float_as_uint(x);
    unsigned int r = (b + 0x7fffu + ((b >> 16) & 1u)) >> 16;
    return (unsigned short)r;
}

// ---------------- convert F f32 -> bf16 ----------------
__global__ __launch_bounds__(256) void cvt_k(const float* __restrict__ F,
                                             unsigned short* __restrict__ Fb) {
    int idx = blockIdx.x * 256 + threadIdx.x;
    float4 v = ((const float4*)F)[idx];
    ushort4 o;
    o.x = f2bf(v.x); o.y = f2bf(v.y); o.z = f2bf(v.z); o.w = f2bf(v.w);
    ((ushort4*)Fb)[idx] = o;
}

// ---------------- single-pass stats kernel ----------------
// 9-sum decomposition (shift-free; see analysis): per row i accumulate
// a=sum_same e^s, b=sum_diff e^s, e1/e2=sum e^l, f1/f2=sum e^l*e^s,
// g=sum_same l, h=sum_same l*e^s, with l=(s-1)/T.
__global__ __launch_bounds__(BLK, 4) void supcon_k(const unsigned short* __restrict__ Fb,
                                                   const int* __restrict__ labels,
                                                   float* __restrict__ partial) {
    __shared__ unsigned short sFi[IB * DD];   // 32 KB, XOR-swizzled 16B cols
    __shared__ int slab[JPC];                 // 2 KB
    float* sred = (float*)sFi;                // aliased after compute: [8][64][8]

    const int tid = threadIdx.x;
    const int lane = tid & 63;
    const int wid = tid >> 6;
    const int il = lane & 15;
    const int kg = lane >> 4;
    const int ib = blockIdx.x >> 3;
    const int jc = blockIdx.x & 7;
    const int i0 = ib * IB;
    const int jbase0 = jc * JPC;

    // stage i-rows into LDS, swizzling 16B column index by (row&7)
    for (int idx = tid; idx < IB * DD / 8; idx += BLK) {
        int row = idx >> 5;
        int c16 = idx & 31;
        short8 v = *(const short8*)(Fb + (size_t)(i0 + row) * DD + c16 * 8);
        *(short8*)(&sFi[row * DD + ((c16 ^ (row & 7)) * 8)]) = v;
    }
    for (int idx = tid; idx < JPC; idx += BLK) slab[idx] = labels[jbase0 + idx];
    __syncthreads();

    int li[4];
#pragma unroll
    for (int it = 0; it < 4; it++) li[it] = labels[i0 + it * 16 + il];

    float sA[4], sB[4], sE1[4], sE2[4], sF1[4], sF2[4], sG[4], sH[4];
#pragma unroll
    for (int it = 0; it < 4; it++) {
        sA[it] = 0.f; sB[it] = 0.f; sE1[it] = 0.f; sE2[it] = 0.f;
        sF1[it] = 0.f; sF2[it] = 0.f; sG[it] = 0.f; sH[it] = 0.f;
    }

    const int swz = il & 7;
    for (int n = 0; n < JT / 8; n++) {
        const int tl = wid + n * 8;
        const int jb = jbase0 + tl * 16;
        const short8* ap = (const short8*)(Fb + (size_t)(jb + il) * DD + kg * 8);
        short8 af[8];
#pragma unroll
        for (int k0 = 0; k0 < 8; k0++) af[k0] = ap[k0 * 4];

        f32x4 acc[4];
#pragma unroll
        for (int it = 0; it < 4; it++) {
            f32x4 c = {0.f, 0.f, 0.f, 0.f};
#pragma unroll
            for (int k0 = 0; k0 < 8; k0++) {
                short8 bf = *(const short8*)(&sFi[(it * 16 + il) * DD + (((kg + k0 * 4) ^ swz) * 8)]);
                c = __builtin_amdgcn_mfma_f32_16x16x32_bf16(af[k0], bf, c, 0, 0, 0);
            }
            acc[it] = c;
        }

        int lj[4];
#pragma unroll
        for (int r = 0; r < 4; r++) lj[r] = slab[tl * 16 + kg * 4 + r];

#pragma unroll
        for (int it = 0; it < 4; it++) {
            const int ig = i0 + it * 16 + il;
#pragma unroll
            for (int r = 0; r < 4; r++) {
                float s = acc[it][r];
                int j = jb + kg * 4 + r;
                bool same = (lj[r] == li[it]);
                float msf = (same && (j != ig)) ? 1.0f : 0.0f;
                float mdf = same ? 0.0f : 1.0f;
                float l = (s - 1.0f) * INV_T;
                float es = __expf(s);
                float el = __expf(l);
                float t = el * es;
                sA[it]  = fmaf(msf, es, sA[it]);
                sB[it]  = fmaf(mdf, es, sB[it]);
                sE1[it] = fmaf(msf, el, sE1[it]);
                sE2[it] = fmaf(mdf, el, sE2[it]);
                sF1[it] = fmaf(msf, t, sF1[it]);
                sF2[it] = fmaf(mdf, t, sF2[it]);
                sG[it]  = fmaf(msf, l, sG[it]);
                sH[it]  = fmaf(msf, l * es, sH[it]);
            }
        }
    }

    // reduce over kg lanes (xor 16, 32): lanes sharing il end with full sums
#pragma unroll
    for (int it = 0; it < 4; it++) {
        sA[it]  += __shfl_xor(sA[it], 16, 64);  sA[it]  += __shfl_xor(sA[it], 32, 64);
        sB[it]  += __shfl_xor(sB[it], 16, 64);  sB[it]  += __shfl_xor(sB[it], 32, 64);
        sE1[it] += __shfl_xor(sE1[it], 16, 64); sE1[it] += __shfl_xor(sE1[it], 32, 64);
        sE2[it] += __shfl_xor(sE2[it], 16, 64); sE2[it] += __shfl_xor(sE2[it], 32, 64);
        sF1[it] += __shfl_xor(sF1[it], 16, 64); sF1[it] += __shfl_xor(sF1[it], 32, 64);
        sF2[it] += __shfl_xor(sF2[it], 16, 64); sF2[it] += __shfl_xor(sF2[it], 32, 64);
        sG[it]  += __shfl_xor(sG[it], 16, 64);  sG[it]  += __shfl_xor(sG[it], 32, 64);
        sH[it]  += __shfl_xor(sH[it], 16, 64);  sH[it]  += __shfl_xor(sH[it], 32, 64);
    }
    __syncthreads();   // done reading sFi; safe to alias as sred
    if (lane < 16) {
#pragma unroll
        for (int it = 0; it < 4; it++) {
            float* p = &sred[(wid * IB + it * 16 + il) * 8];
            p[0] = sA[it];  p[1] = sB[it];  p[2] = sE1[it]; p[3] = sE2[it];
            p[4] = sF1[it]; p[5] = sF2[it]; p[6] = sG[it];  p[7] = sH[it];
        }
    }
    __syncthreads();
    {
        const int row = tid >> 3, k = tid & 7;   // 512 threads = 64 rows x 8 stats
        float v = 0.f;
#pragma unroll
        for (int w = 0; w < 8; w++) v += sred[(w * IB + row) * 8 + k];
        partial[((size_t)jc * NN + i0 + row) * 8 + k] = v;
    }
}

// ---------------- finalize: merge chunks, compute loss ----------------
__global__ __launch_bounds__(256) void finalize_k(const float* __restrict__ partial,
                                                  const int* __restrict__ labels,
                                                  float* __restrict__ out) {
    __shared__ int hist[16];
    __shared__ float sacc[4];
    const int t = threadIdx.x;
    if (t < 16) hist[t] = 0;
    __syncthreads();
    for (int j = t; j < NN; j += 256) atomicAdd(&hist[labels[j] & 15], 1);
    __syncthreads();

    const int i = blockIdx.x * 256 + t;
    float st[8];
#pragma unroll
    for (int k = 0; k < 8; k++) st[k] = 0.f;
    for (int jc = 0; jc < JC; jc++) {
#pragma unroll
        for (int k = 0; k < 8; k++) st[k] += partial[((size_t)jc * NN + i) * 8 + k];
    }
    float a = st[0], b = st[1], e1 = st[2], e2 = st[3];
    float f1 = st[4], f2 = st[5], g = st[6], h = st[7];
    float c = (float)(hist[labels[i] & 15] - 1);
    float As = (a > 0.f) ? a : 1.f;
    float Ad = (b > 0.f) ? b : 1.f;
    float Z = e1 + e2 + f2 / Ad - f1 / As;
    float Q = g - h / As;
    float P = c - a / As;        // = c-1 when a>0, 0 when empty
    float ms = (c > 0.f) ? c : 1.f;
    float loss_i = -(Q - P * logf(Z + 1e-8f)) / ms;

    float v = loss_i;
#pragma unroll
    for (int off = 32; off > 0; off >>= 1) v += __shfl_xor(v, off, 64);
    if ((t & 63) == 0) sacc[t >> 6] = v;
    __syncthreads();
    if (t == 0) atomicAdd(out, (sacc[0] + sacc[1] + sacc[2] + sacc[3]) * (1.0f / NN));
}

extern "C" void kernel_launch(void* const* d_in, const int* in_sizes, int n_in,
                              void* d_out, int out_size, void* d_ws, size_t ws_size,
                              hipStream_t stream) {
    const float* F = (const float*)d_in[0];
    const int* labels = (const int*)d_in[1];
    float* out = (float*)d_out;
    unsigned short* Fb = (unsigned short*)d_ws;                 // 2 MB
    float* partial = (float*)((char*)d_ws + (size_t)NN * DD * 2); // 1 MB (JC*NN*8 floats)

    hipMemsetAsync(out, 0, sizeof(float), stream);
    cvt_k<<<NN * DD / 4 / 256, 256, 0, stream>>>(F, Fb);
    supcon_k<<<(NN / IB) * JC, BLK, 0, stream>>>(Fb, labels, partial);
    finalize_k<<<NN / 256, 256, 0, stream>>>(partial, labels, out);
}